// Round 2
// baseline (325.258 us; speedup 1.0000x reference)
//
#include <hip/hip_runtime.h>
#include <stdint.h>
#include <stddef.h>

typedef _Float16 f16;
typedef __attribute__((ext_vector_type(8))) _Float16 f16x8;
typedef __attribute__((ext_vector_type(4))) float f32x4;

#define GPTR(p) ((const __attribute__((address_space(1))) void*)(p))
#define LPTR(p) ((__attribute__((address_space(3))) void*)(p))

// async global->LDS, 16B per lane; LDS dest = wave-uniform base + lane*16
__device__ __forceinline__ void async16(const void* g, void* l) {
    __builtin_amdgcn_global_load_lds(GPTR(g), LPTR(l), 16, 0, 0);
}

#define VMCNT(N) asm volatile("s_waitcnt vmcnt(" #N ")" ::: "memory")
#define SBAR()   do { __builtin_amdgcn_sched_barrier(0); \
                      __builtin_amdgcn_s_barrier();      \
                      __builtin_amdgcn_sched_barrier(0); } while (0)

// ---------------------------------------------------------------------------
// Sparsify (2:4 soft-threshold along last dim of W[K][M]) * scale -> fp16,
// stored transposed AND tile-padded: Wp[kt][M][80B] where kt = k/32.
// Each 80B row = 64B (32 f16 of k-chunk) + 16B pad -> LDS rows land on odd
// slot stride (5) => conflict-free ds_read_b128, and staging is pure linear.
// ---------------------------------------------------------------------------
__global__ __launch_bounds__(256) void sparsify_t_pad(
        const float* __restrict__ W, const float* __restrict__ scale,
        f16* __restrict__ Wp, int K, int M) {
    __shared__ f16 T[64][80];
    const int r0 = blockIdx.y << 6, m0 = blockIdx.x << 6;   // r0: k-dim, m0: out-row
    const float s = scale[0];
    const int t = threadIdx.x;
    const int rr = t >> 2, mb = (t & 3) << 4;
    const float* src = W + (size_t)(r0 + rr) * M + m0 + mb;
    #pragma unroll
    for (int j = 0; j < 4; j++) {
        float4 v = *(const float4*)(src + j * 4);
        float a0 = fabsf(v.x), a1 = fabsf(v.y), a2 = fabsf(v.z), a3 = fabsf(v.w);
        float lo1 = fminf(a0, a1), hi1 = fmaxf(a0, a1);
        float lo2 = fminf(a2, a3), hi2 = fmaxf(a2, a3);
        float th = fminf(fmaxf(lo1, lo2), fminf(hi1, hi2));
        int m = mb + j * 4;
        T[m + 0][rr] = (f16)(copysignf(fmaxf(a0 - th, 0.f), v.x) * s);
        T[m + 1][rr] = (f16)(copysignf(fmaxf(a1 - th, 0.f), v.y) * s);
        T[m + 2][rr] = (f16)(copysignf(fmaxf(a2 - th, 0.f), v.z) * s);
        T[m + 3][rr] = (f16)(copysignf(fmaxf(a3 - th, 0.f), v.w) * s);
    }
    __syncthreads();
    const int mm = t >> 2, rb = (t & 3) << 4;       // rb in {0,16,32,48}
    const int k  = r0 + rb;
    f16* dst = Wp + ((size_t)(k >> 5) * M + (m0 + mm)) * 40 + (k & 31);
    *(f16x8*)dst       = *(const f16x8*)&T[mm][rb];
    *(f16x8*)(dst + 8) = *(const f16x8*)&T[mm][rb + 8];
}

// ---------------------------------------------------------------------------
// GEMM1: Hp = fp16(x[16384][2048]) @ W1t^T + b1, output in padded-tile layout.
// BM=64, BN=256 (A read once), BK=32, NT=64. 512 thr = 8 waves (2m x 4n).
// LDS per stage: A 64x144B (pad, slot mult 9) + B 256x80B linear = 29696B.
// 3-deep buffers (89 KB). Uniform 4 DMA issues/wave (dups pad), VMCNT(8).
// No source swizzle: all staging line-coalesced.
// ---------------------------------------------------------------------------
__global__ __launch_bounds__(512, 2) void gemm1_kernel(
        const float* __restrict__ A, const f16* __restrict__ B1p,
        const float* __restrict__ bias, f16* __restrict__ Hp) {
    constexpr int K = 2048, BK = 32, NT = K / BK;
    constexpr int NROWS = 16384;
    constexpr int ABYTES = 64 * 144;            // 9216
    constexpr int STAGE  = ABYTES + 256 * 80;   // 29696 (16B-aligned)
    __shared__ char lds[3][STAGE];

    const int tid  = threadIdx.x;
    const int lane = tid & 63;
    const int wv   = tid >> 6;
    const int wm   = wv & 1, wn = wv >> 1;
    const int lr   = lane & 15, q = lane >> 4;
    const int row0 = blockIdx.x << 6;

    f32x4 acc[2][4] = {};

    // ---- per-lane staging sources: 29 real issues (A:9, B:20), 4 slots/wave
    const char* sp[4];
    size_t step[4];
    int dg[4];
    #pragma unroll
    for (int j = 0; j < 4; j++) {
        int g = (wv < 5) ? (wv * 4 + j) : (20 + (wv - 5) * 3 + (j < 2 ? j : 2));
        dg[j] = g * 1024;
        if (g < 9) {                            // A issue: 144B-stride rows
            int o = g * 1024 + (lane << 4);
            int r = o / 144;
            int w = o - r * 144;
            if (w >= 128) w = 0;                // pad lane: benign dup of row start
            sp[j] = (const char*)(A + (size_t)(row0 + r) * K) + w;
            step[j] = BK * 4;                   // advance 32 floats per tile
        } else {                                // B issue: pre-padded, pure linear
            sp[j] = (const char*)B1p + (size_t)(g - 9) * 1024 + (lane << 4);
            step[j] = 256 * 80;                 // one padded k-tile
        }
    }

    auto stage = [&](char* buf) {
        #pragma unroll
        for (int j = 0; j < 4; j++) { async16(sp[j], buf + dg[j]); sp[j] += step[j]; }
    };

    auto compute = [&](const char* buf) {
        const char* Ab = buf;
        const char* Bb = buf + ABYTES;
        f16x8 af[2], bf[4];
        #pragma unroll
        for (int m = 0; m < 2; m++) {
            int r = wm * 32 + m * 16 + lr;
            const float4* va = (const float4*)(Ab + r * 144 + q * 32);
            float4 v0 = va[0], v1 = va[1];
            f16x8 h;
            h[0] = (f16)v0.x; h[1] = (f16)v0.y; h[2] = (f16)v0.z; h[3] = (f16)v0.w;
            h[4] = (f16)v1.x; h[5] = (f16)v1.y; h[6] = (f16)v1.z; h[7] = (f16)v1.w;
            af[m] = h;
        }
        #pragma unroll
        for (int n = 0; n < 4; n++) {
            int r = wn * 64 + n * 16 + lr;
            bf[n] = *(const f16x8*)(Bb + r * 80 + q * 16);
        }
        #pragma unroll
        for (int m = 0; m < 2; m++)
            #pragma unroll
            for (int n = 0; n < 4; n++)
                acc[m][n] = __builtin_amdgcn_mfma_f32_16x16x32_f16(
                    af[m], bf[n], acc[m][n], 0, 0, 0);
    };

    char* p0 = lds[0];
    char* p1 = lds[1];
    char* p2 = lds[2];
    stage(p0);                  // tile 0
    stage(p1);                  // tile 1
    for (int t = 0; t < NT - 2; ++t) {
        stage(p2);              // tile t+2
        VMCNT(8);               // tile t's 4 loads done; t+1,t+2 in flight
        SBAR();
        compute(p0);
        SBAR();                 // p2's old contents now fully consumed last iter
        char* tmp = p0; p0 = p1; p1 = p2; p2 = tmp;
    }
    VMCNT(4); SBAR(); compute(p0);          // tile NT-2
    VMCNT(0); SBAR(); compute(p1);          // tile NT-1

    // epilogue: write H in padded-tile layout Hp[kt][NROWS][80B]
    #pragma unroll
    for (int m = 0; m < 2; m++) {
        int gr0 = row0 + wm * 32 + m * 16 + q * 4;
        #pragma unroll
        for (int n = 0; n < 4; n++) {
            int gc = wn * 64 + n * 16 + lr;
            float bv = bias[gc];
            f16* hbase = Hp + (size_t)(gc >> 5) * NROWS * 40 + (gc & 31);
            #pragma unroll
            for (int r = 0; r < 4; r++)
                hbase[(size_t)(gr0 + r) * 40] = (f16)(acc[m][n][r] + bv);
        }
    }
}

// ---------------------------------------------------------------------------
// GEMM2: y[16384][2048](f32) = H @ W2t^T + b2.
// BM=128, BN=256, BK=32, NT=8. 512 thr = 8 waves (2m x 4n, 64x64 wave-tiles).
// A from padded Hp, B from padded W2p: all staging pure linear 1KB bursts.
// 2-deep buffers (60 KB). 30 real issues -> uniform 4/wave, VMCNT(4).
// Write-bound (134 MB Y) -> floor ~21 us.
// ---------------------------------------------------------------------------
__global__ __launch_bounds__(512, 2) void gemm2_kernel(
        const f16* __restrict__ Hp, const f16* __restrict__ B2p,
        const float* __restrict__ bias, float* __restrict__ Y) {
    constexpr int NROWS = 16384, N = 2048, NT = 8;
    constexpr int ABYTES = 128 * 80;            // 10240
    constexpr int STAGE  = ABYTES + 256 * 80;   // 30720
    __shared__ char lds[2][STAGE];

    const int tid  = threadIdx.x;
    const int lane = tid & 63;
    const int wv   = tid >> 6;
    const int wm   = wv & 1, wn = wv >> 1;
    const int lr   = lane & 15, q = lane >> 4;
    const int row0 = blockIdx.y << 7;
    const int col0 = blockIdx.x << 8;

    f32x4 acc[4][4] = {};

    const char* sp[4];
    size_t step[4];
    int dg[4];
    #pragma unroll
    for (int j = 0; j < 4; j++) {
        int g = (wv < 6) ? (wv * 4 + j) : (24 + (wv - 6) * 3 + (j < 2 ? j : 2));
        dg[j] = g * 1024;
        if (g < 10) {                           // A: Hp[t][row0..row0+128][80]
            sp[j] = (const char*)Hp + (size_t)row0 * 80 + g * 1024 + (lane << 4);
            step[j] = (size_t)NROWS * 80;
        } else {                                // B: W2p[t][col0..col0+256][80]
            sp[j] = (const char*)B2p + (size_t)col0 * 80 + (size_t)(g - 10) * 1024
                    + (lane << 4);
            step[j] = (size_t)2048 * 80;
        }
    }

    auto stage = [&](char* buf) {
        #pragma unroll
        for (int j = 0; j < 4; j++) { async16(sp[j], buf + dg[j]); sp[j] += step[j]; }
    };

    auto compute = [&](const char* buf) {
        const char* Ab = buf;
        const char* Bb = buf + ABYTES;
        f16x8 af[4], bf[4];
        #pragma unroll
        for (int m = 0; m < 4; m++) {
            int r = wm * 64 + m * 16 + lr;
            af[m] = *(const f16x8*)(Ab + r * 80 + q * 16);
        }
        #pragma unroll
        for (int n = 0; n < 4; n++) {
            int r = wn * 64 + n * 16 + lr;
            bf[n] = *(const f16x8*)(Bb + r * 80 + q * 16);
        }
        #pragma unroll
        for (int m = 0; m < 4; m++)
            #pragma unroll
            for (int n = 0; n < 4; n++)
                acc[m][n] = __builtin_amdgcn_mfma_f32_16x16x32_f16(
                    af[m], bf[n], acc[m][n], 0, 0, 0);
    };

    char* p0 = lds[0];
    char* p1 = lds[1];
    stage(p0);                                  // tile 0
    for (int t = 0; t < NT - 1; ++t) {
        stage(p1);                              // tile t+1
        VMCNT(4);                               // tile t done; t+1 in flight
        SBAR();
        compute(p0);
        SBAR();
        char* tmp = p0; p0 = p1; p1 = tmp;
    }
    VMCNT(0); SBAR(); compute(p0);              // tile NT-1

    #pragma unroll
    for (int m = 0; m < 4; m++) {
        int gr0 = row0 + wm * 64 + m * 16 + q * 4;
        #pragma unroll
        for (int n = 0; n < 4; n++) {
            int gc = col0 + wn * 64 + n * 16 + lr;
            float bv = bias[gc];
            #pragma unroll
            for (int r = 0; r < 4; r++)
                Y[(size_t)(gr0 + r) * N + gc] = acc[m][n][r] + bv;
        }
    }
}

// ---------------------------------------------------------------------------
// launch
// ---------------------------------------------------------------------------
extern "C" void kernel_launch(void* const* d_in, const int* in_sizes, int n_in,
                              void* d_out, int out_size, void* d_ws, size_t ws_size,
                              hipStream_t stream) {
    const float* x  = (const float*)d_in[0];   // [8,2048,2048]
    const float* w1 = (const float*)d_in[1];   // [2048,256]
    const float* w2 = (const float*)d_in[2];   // [256,2048]
    const float* b1 = (const float*)d_in[3];   // [256]
    const float* b2 = (const float*)d_in[4];   // [2048]
    const float* s1 = (const float*)d_in[5];   // [1]
    const float* s2 = (const float*)d_in[6];   // [1]
    float* y = (float*)d_out;                  // [8,2048,2048] fp32

    constexpr int NROWS = 8 * 2048;  // 16384
    constexpr int D = 2048, R = 256;

    char* ws = (char*)d_ws;
    // padded-tile layouts: row stride 80B, tiles of 32 k each
    f16* W1p = (f16*)ws;                               // [64][256][80B]  = 1.25 MiB
    f16* W2p = (f16*)(ws + (2u << 20));                // [8][2048][80B]  = 1.25 MiB
    f16* Hp  = (f16*)(ws + (4u << 20));                // [8][16384][80B] = 10 MiB

    // sparsify + transpose + pad both weights
    hipLaunchKernelGGL(sparsify_t_pad, dim3(R / 64, D / 64), dim3(256),
                       0, stream, w1, s1, W1p, D, R);
    hipLaunchKernelGGL(sparsify_t_pad, dim3(D / 64, R / 64), dim3(256),
                       0, stream, w2, s2, W2p, R, D);

    // GEMM1: 256 blocks, 64-row panel each, full N=256 (A read once)
    hipLaunchKernelGGL(gemm1_kernel, dim3(NROWS / 64), dim3(512),
                       0, stream, x, W1p, b1, Hp);

    // GEMM2: 8 x 128 = 1024 blocks
    hipLaunchKernelGGL(gemm2_kernel, dim3(D / 256, NROWS / 128), dim3(512),
                       0, stream, Hp, W2p, b2, y);
}

// Round 3
// 290.693 us; speedup vs baseline: 1.1189x; 1.1189x over previous
//
#include <hip/hip_runtime.h>
#include <stdint.h>
#include <stddef.h>

typedef _Float16 f16;
typedef __attribute__((ext_vector_type(8))) _Float16 f16x8;
typedef __attribute__((ext_vector_type(4))) float f32x4;

#define GPTR(p) ((const __attribute__((address_space(1))) void*)(p))
#define LPTR(p) ((__attribute__((address_space(3))) void*)(p))

// async global->LDS, 16B per lane; LDS dest = wave-uniform base + lane*16
__device__ __forceinline__ void async16(const void* g, void* l) {
    __builtin_amdgcn_global_load_lds(GPTR(g), LPTR(l), 16, 0, 0);
}

// ---------------------------------------------------------------------------
// Sparsify (2:4 soft-threshold along last dim of W[K][M]) * scale -> fp16,
// stored in MFMA-fragment order: 16B block idx =
//   ((k>>5)*(M/16) + (col>>4))*64 + ((k>>3)&3)*16 + (col&15),  elem e = k&7.
// A wave's B-fragment read then = wave-uniform base + lane*16 (conflict-free),
// and GEMM staging of one (kt,c16) chunk is 1KB contiguous (perfectly
// coalesced global_load_lds).
// ---------------------------------------------------------------------------
__global__ __launch_bounds__(256) void sparsify_frag(
        const float* __restrict__ W, const float* __restrict__ scale,
        f16* __restrict__ Wf, int K, int M) {
    __shared__ f16 T[64][80];
    const int r0 = blockIdx.y << 6, m0 = blockIdx.x << 6;   // r0: k-dim, m0: col
    const float s = scale[0];
    const int t = threadIdx.x;
    const int rr = t >> 2, mb = (t & 3) << 4;
    const float* src = W + (size_t)(r0 + rr) * M + m0 + mb;
    #pragma unroll
    for (int j = 0; j < 4; j++) {
        float4 v = *(const float4*)(src + j * 4);
        float a0 = fabsf(v.x), a1 = fabsf(v.y), a2 = fabsf(v.z), a3 = fabsf(v.w);
        float lo1 = fminf(a0, a1), hi1 = fmaxf(a0, a1);
        float lo2 = fminf(a2, a3), hi2 = fmaxf(a2, a3);
        float th = fminf(fmaxf(lo1, lo2), fminf(hi1, hi2));
        int m = mb + j * 4;
        T[m + 0][rr] = (f16)(copysignf(fmaxf(a0 - th, 0.f), v.x) * s);
        T[m + 1][rr] = (f16)(copysignf(fmaxf(a1 - th, 0.f), v.y) * s);
        T[m + 2][rr] = (f16)(copysignf(fmaxf(a2 - th, 0.f), v.z) * s);
        T[m + 3][rr] = (f16)(copysignf(fmaxf(a3 - th, 0.f), v.w) * s);
    }
    __syncthreads();
    const int mm = t >> 2, rb = (t & 3) << 4;
    const int col = m0 + mm;
    const int Mb = M >> 4;
    #pragma unroll
    for (int h = 0; h < 2; h++) {
        int k = r0 + rb + h * 8;
        size_t blk = ((size_t)(k >> 5) * Mb + (col >> 4)) * 64
                   + (size_t)(((k >> 3) & 3) * 16 + (col & 15));
        *(f16x8*)(Wf + blk * 8) = *(const f16x8*)&T[mm][rb + h * 8];
    }
}

// ---------------------------------------------------------------------------
// GEMM1: Hf = fp16(x[16384][2048]) @ W1f + b1   (Hf in fragment order)
// m97-like: BM=64 BN=64 BK=64, 256 thr (2x2 waves of 32x32), single-buffer
// 24KB LDS, plain __syncthreads loop -> 1024 blocks = 4 blocks/CU.
// XCD-pairing swizzle: the 4 col-blocks of an A-panel share one XCD's L2.
// A: f32 LDS with within-row 16B-chunk XOR (conflict-free phases).
// B: fragment-order -> linear staging, linear conflict-free reads.
// ---------------------------------------------------------------------------
__global__ __launch_bounds__(256, 4) void gemm1_kernel(
        const float* __restrict__ A, const f16* __restrict__ Bf,
        const float* __restrict__ bias, f16* __restrict__ Hf) {
    constexpr int K = 2048, BK = 64, NT = K / BK;
    __shared__ float4 Asf[64 * 16];   // 16 KB  [row][16 chunks, XOR-swizzled]
    __shared__ f16x8  Bs[8 * 64];     //  8 KB  [ks*4 + c16][lane]

    const int tid = threadIdx.x, lane = tid & 63, wv = tid >> 6;
    const int wm = wv & 1, wn = wv >> 1;
    const int lr = lane & 15, q = lane >> 4;

    // swizzle: 4 n-blocks of panel p -> ids == p%8 (mod 8) -> same XCD
    const int id = blockIdx.x + (blockIdx.y << 2);
    const int xr = id & 7, xt = id >> 3;
    const int nb = xt & 3, p = xr + ((xt >> 2) << 3);
    const int row0 = p << 6, col0 = nb << 6;

    f32x4 acc[2][2] = {};

    // A staging: 16 issues of 1KB (4 rows each), this wave does 4.
    // chunk swizzle c' = (c&8) | ((c&7)^(r&7)) stays within the 128B half-row.
    const float* aSrc[4];
    #pragma unroll
    for (int j = 0; j < 4; j++) {
        int i = wv * 4 + j;
        int r = i * 4 + (lane >> 4);
        int c = lane & 15;
        int cs = (c & 8) | ((c & 7) ^ (r & 7));
        aSrc[j] = A + (size_t)(row0 + r) * K + cs * 4;
    }
    // B staging: 8 chunks of 1KB (contiguous in Bf), this wave does 2.
    const f16* bSrc[2];
    #pragma unroll
    for (int j = 0; j < 2; j++) {
        int ch = wv * 2 + j;               // s = ch>>2 (kt32), c16 = ch&3
        int s = ch >> 2, c = ch & 3;
        bSrc[j] = Bf + (((size_t)s * 16 + (col0 >> 4) + c) * 64) * 8 + lane * 8;
    }

    for (int t = 0; t < NT; ++t) {
        #pragma unroll
        for (int j = 0; j < 4; j++) {
            int i = wv * 4 + j;
            async16(aSrc[j], (char*)Asf + i * 1024);
            aSrc[j] += BK;
        }
        #pragma unroll
        for (int j = 0; j < 2; j++) {
            int ch = wv * 2 + j;
            async16(bSrc[j], (char*)Bs + ch * 1024);
            bSrc[j] += 2 * 16 * 64 * 8;    // advance 2 kt32 tiles (f16 units)
        }
        __syncthreads();
        #pragma unroll
        for (int ks = 0; ks < 2; ks++) {
            f16x8 af[2], bf[2];
            #pragma unroll
            for (int m = 0; m < 2; m++) {
                int r = wm * 32 + m * 16 + lr;
                float4 v0 = Asf[r * 16 + (ks * 8 + ((2 * q)     ^ (r & 7)))];
                float4 v1 = Asf[r * 16 + (ks * 8 + ((2 * q + 1) ^ (r & 7)))];
                f16x8 h;
                h[0] = (f16)v0.x; h[1] = (f16)v0.y; h[2] = (f16)v0.z; h[3] = (f16)v0.w;
                h[4] = (f16)v1.x; h[5] = (f16)v1.y; h[6] = (f16)v1.z; h[7] = (f16)v1.w;
                af[m] = h;
            }
            #pragma unroll
            for (int n = 0; n < 2; n++)
                bf[n] = Bs[(ks * 4 + wn * 2 + n) * 64 + lane];
            #pragma unroll
            for (int m = 0; m < 2; m++)
                #pragma unroll
                for (int n = 0; n < 2; n++)
                    acc[m][n] = __builtin_amdgcn_mfma_f32_16x16x32_f16(
                        af[m], bf[n], acc[m][n], 0, 0, 0);
        }
        __syncthreads();
    }

    // epilogue: write H in fragment order (gemm2's A layout, M/16 = 1024)
    #pragma unroll
    for (int m = 0; m < 2; m++) {
        int r16 = (row0 + wm * 32 + m * 16) >> 4;
        #pragma unroll
        for (int n = 0; n < 2; n++) {
            int gc = col0 + wn * 32 + n * 16 + lr;
            float bv = bias[gc];
            int kt = gc >> 5, qq = (gc >> 3) & 3, e = gc & 7;
            f16* hb = Hf + ((((size_t)kt * 1024 + r16) * 4 + qq) * 16) * 8 + e;
            #pragma unroll
            for (int rr = 0; rr < 4; rr++)
                hb[(q * 4 + rr) * 8] = (f16)(acc[m][n][rr] + bv);
        }
    }
}

// ---------------------------------------------------------------------------
// GEMM2: y[16384][2048](f32) = H @ W2f + b2.   BM=128 BN=64 BK=64, NT=4.
// 256 thr (2x2 waves of 64x32), single-buffer 24KB, 4096 blocks = 4/CU.
// Both operands fragment-order: all staging linear 1KB chunks, all LDS
// fragment reads = base + lane*16 (conflict-free), no cvt in loop.
// Co-XCD swizzle on row panels (H re-reads -> local L2).
// ---------------------------------------------------------------------------
__global__ __launch_bounds__(256, 4) void gemm2_kernel(
        const f16* __restrict__ Hf, const f16* __restrict__ Bf,
        const float* __restrict__ bias, float* __restrict__ Y) {
    constexpr int N = 2048, NT = 4;
    __shared__ f16x8 As[16 * 64];   // 16 KB  [s*8 + r16][lane]
    __shared__ f16x8 Bs[8 * 64];    //  8 KB  [s*4 + c16][lane]

    const int tid = threadIdx.x, lane = tid & 63, wv = tid >> 6;
    const int wm = wv & 1, wn = wv >> 1;
    const int lr = lane & 15, q = lane >> 4;

    const int id = blockIdx.x + (blockIdx.y << 5);
    const int xr = id & 7, xt = id >> 3;
    const int bx = xt & 31, by = xr + ((xt >> 5) << 3);
    const int row0 = by << 7, col0 = bx << 6;

    f32x4 acc[4][2] = {};

    for (int t = 0; t < NT; ++t) {
        int kt0 = 2 * t;
        // A: 16 issues (1KB each = one (kt, r16) block), 4 per wave
        #pragma unroll
        for (int j = 0; j < 4; j++) {
            int i = wv * 4 + j;
            int s = i >> 3, rb = i & 7;
            const f16* srcp = Hf + (((size_t)(kt0 + s) * 1024 + (row0 >> 4) + rb) * 64) * 8
                              + lane * 8;
            async16(srcp, (char*)As + i * 1024);
        }
        // B: 8 issues, 2 per wave
        #pragma unroll
        for (int j = 0; j < 2; j++) {
            int ch = wv * 2 + j;
            int s = ch >> 2, c = ch & 3;
            const f16* srcp = Bf + (((size_t)(kt0 + s) * 128 + (col0 >> 4) + c) * 64) * 8
                              + lane * 8;
            async16(srcp, (char*)Bs + ch * 1024);
        }
        __syncthreads();
        #pragma unroll
        for (int ks = 0; ks < 2; ks++) {
            f16x8 af[4], bf[2];
            #pragma unroll
            for (int m = 0; m < 4; m++)
                af[m] = As[(ks * 8 + wm * 4 + m) * 64 + lane];
            #pragma unroll
            for (int n = 0; n < 2; n++)
                bf[n] = Bs[(ks * 4 + wn * 2 + n) * 64 + lane];
            #pragma unroll
            for (int m = 0; m < 4; m++)
                #pragma unroll
                for (int n = 0; n < 2; n++)
                    acc[m][n] = __builtin_amdgcn_mfma_f32_16x16x32_f16(
                        af[m], bf[n], acc[m][n], 0, 0, 0);
        }
        __syncthreads();
    }

    #pragma unroll
    for (int m = 0; m < 4; m++) {
        int gr0 = row0 + wm * 64 + m * 16 + q * 4;
        #pragma unroll
        for (int n = 0; n < 2; n++) {
            int gc = col0 + wn * 32 + n * 16 + lr;
            float bv = bias[gc];
            #pragma unroll
            for (int rr = 0; rr < 4; rr++)
                Y[(size_t)(gr0 + rr) * N + gc] = acc[m][n][rr] + bv;
        }
    }
}

// ---------------------------------------------------------------------------
// launch
// ---------------------------------------------------------------------------
extern "C" void kernel_launch(void* const* d_in, const int* in_sizes, int n_in,
                              void* d_out, int out_size, void* d_ws, size_t ws_size,
                              hipStream_t stream) {
    const float* x  = (const float*)d_in[0];   // [8,2048,2048]
    const float* w1 = (const float*)d_in[1];   // [2048,256]
    const float* w2 = (const float*)d_in[2];   // [256,2048]
    const float* b1 = (const float*)d_in[3];   // [256]
    const float* b2 = (const float*)d_in[4];   // [2048]
    const float* s1 = (const float*)d_in[5];   // [1]
    const float* s2 = (const float*)d_in[6];   // [1]
    float* y = (float*)d_out;                  // [8,2048,2048] fp32

    constexpr int NROWS = 8 * 2048;  // 16384
    constexpr int D = 2048, R = 256;

    char* ws = (char*)d_ws;
    f16* W1f = (f16*)ws;                   // fragment-order [64][16][4][16][8], 1 MiB
    f16* W2f = (f16*)(ws + (2u << 20));    // fragment-order [8][128][4][16][8], 1 MiB
    f16* Hf  = (f16*)(ws + (4u << 20));    // fragment-order [8][1024][4][16][8], 8 MiB

    hipLaunchKernelGGL(sparsify_frag, dim3(R / 64, D / 64), dim3(256),
                       0, stream, w1, s1, W1f, D, R);
    hipLaunchKernelGGL(sparsify_frag, dim3(D / 64, R / 64), dim3(256),
                       0, stream, w2, s2, W2f, R, D);

    // GEMM1: 4 x 256 = 1024 blocks (4/CU), XCD-paired A-panel sharing
    hipLaunchKernelGGL(gemm1_kernel, dim3(4, NROWS / 64), dim3(256),
                       0, stream, x, W1f, b1, Hf);

    // GEMM2: 32 x 128 = 4096 blocks (4/CU)
    hipLaunchKernelGGL(gemm2_kernel, dim3(D / 64, NROWS / 128), dim3(256),
                       0, stream, Hf, W2f, b2, y);
}